// Round 3
// baseline (350.520 us; speedup 1.0000x reference)
//
#include <hip/hip_runtime.h>

#define TT 512
#define II 10
#define HH 32
#define LOG2E 1.44269504088896340736f

typedef __attribute__((ext_vector_type(8))) short bf16x8;   // MFMA A/B frag (4 VGPRs)
typedef __attribute__((ext_vector_type(4))) float f32x4;    // MFMA C/D frag
typedef __attribute__((ext_vector_type(4))) int   i32x4;

#define MFMA(A, B, C) __builtin_amdgcn_mfma_f32_16x16x32_bf16((A), (B), (C), 0, 0, 0)

static __device__ __forceinline__ float frcp(float v) { return __builtin_amdgcn_rcpf(v); }
static __device__ __forceinline__ float fexp2(float v) { return __builtin_amdgcn_exp2f(v); }

static __device__ __forceinline__ short bf16rne(float f) {
    unsigned u = __builtin_bit_cast(unsigned, f);
    u += 0x7fffu + ((u >> 16) & 1u);
    return (short)(u >> 16);
}
// {bf16(a) lo, bf16(b) hi} by truncation: 1 v_perm_b32
static __device__ __forceinline__ unsigned pk2(float a, float b) {
    return __builtin_amdgcn_perm(__builtin_bit_cast(unsigned, b),
                                 __builtin_bit_cast(unsigned, a), 0x07060302u);
}
// same but round-to-nearest (h feeds 512 recurrent steps; avoid trunc bias)
static __device__ __forceinline__ unsigned pkh(float a, float b) {
    return __builtin_amdgcn_perm(__builtin_bit_cast(unsigned, b) + 0x8000u,
                                 __builtin_bit_cast(unsigned, a) + 0x8000u, 0x07060302u);
}

// MFMA LSTM, 2 waves / 16 batch rows per block, 4 subtiles per wave.
// R2 post-mortem: with 2 subtiles/wave the step was latency-bound -- each
// wave had only ~180cy of issue against a ~500cy fixed path (LDS round-trip
// + trans chain + barrier), so SIMDs idled ~80%. Doubling per-wave work
// amortizes the fixed path.
//
// K-permutation pi(q*8+j) = 4j+q partitions perfectly at 2 waves: wave wp
// owns subtiles s = 4wp..4wp+3, so lane (n,q) produces h for units
// {16wp+q, 16wp+4+q, 16wp+8+q, 16wp+12+q} = exactly B_h dword pair
// (b_{2wp}, b_{2wp+1}). Own pair stays IN REGISTERS (no LDS round-trip for
// half the operand); only the partner pair crosses LDS: one ds_write_b64 +
// one ds_read_b64 per lane per step, one 2-wave barrier.
// Sync is lgkm-only (s_waitcnt lgkmcnt(0); s_barrier) so the distance-2
// x prefetch stays in flight across the barrier (validated in R2).
// Weights pre-scaled by log2e (g-gate 2*log2e): unified rcp(1+exp2(-s))
// activations; bias rides the x-MFMA at k=10 with B=1.0.
extern "C" __global__ __launch_bounds__(128)
__attribute__((amdgpu_waves_per_eu(1)))
void lstm_mfma(const float* __restrict__ x,
               const float* __restrict__ h0,
               const float* __restrict__ c0,
               const float* __restrict__ W_ih,
               const float* __restrict__ W_hh,
               const float* __restrict__ b_ih,
               const float* __restrict__ b_hh,
               const float* __restrict__ W_lin,
               const float* __restrict__ b_lin,
               float* __restrict__ out)
{
    __shared__ int2  hx2[2][2][16][4];   // [buf][wp][n][q] partner-pair dwords
    __shared__ float plds[32];

    const int tid  = threadIdx.x;
    const int wp   = tid >> 6;         // wave 0/1 within the chain
    const int lane = tid & 63;
    const int n    = lane & 15;        // batch col (and A-frag row m)
    const int q    = lane >> 4;        // k-chunk / C row-group
    const int R    = blockIdx.x * 16;
    const int row  = R + n;

    // ---- A-frags (weights), one-time. A[m=n][k=q*8+j]. ----
    // gate row in subtile s: G = 16s+n -> unit = 4s+(n>>2), gate = n&3.
    // h-part column = pi(k) = 4j+q. x-part column = k (unpermuted).
    const int   gate = n & 3;
    const float sc   = (gate == 2) ? 2.0f * LOG2E : LOG2E;

    bf16x8 Ah[4], Ax[4];
    float  c[4], wl[4], hv[4];
    #pragma unroll
    for (int i = 0; i < 4; ++i) {
        const int s     = 4 * wp + i;
        const int unitm = 4 * s + (n >> 2);
        const int Wr    = gate * HH + unitm;
        #pragma unroll
        for (int j = 0; j < 8; ++j) {
            Ah[i][j] = bf16rne(W_hh[Wr * HH + 4 * j + q] * sc);
            const int k = q * 8 + j;
            float xv = 0.0f;
            if (k < II)       xv = W_ih[Wr * II + k] * sc;
            else if (k == II) xv = (b_ih[Wr] + b_hh[Wr]) * sc;   // bias (B has 1.0 at k=10)
            Ax[i][j] = bf16rne(xv);
        }
        const int u = 4 * s + q;               // unit this lane owns in subtile s
        c[i]  = c0[row * HH + u];
        wl[i] = W_lin[u];
        hv[i] = 0.0f;
    }

    // own B_h dword pair (b_{2wp}, b_{2wp+1}) -- lives in registers
    int myD0 = (int)pkh(h0[row * HH + 16 * wp + q],     h0[row * HH + 16 * wp + 4 + q]);
    int myD1 = (int)pkh(h0[row * HH + 16 * wp + 8 + q], h0[row * HH + 16 * wp + 12 + q]);
    hx2[0][wp][n][q] = make_int2(myD0, myD1);   // publish for partner, buf 0
    __syncthreads();   // one-time full sync is fine

    // x: lane holds its batch row's 10 floats; two reg sets -> prefetch dist 2
    const float* xp = x + (size_t)row * (TT * II);
    float2 e0 = *(const float2*)(xp + 0), e1 = *(const float2*)(xp + 2),
           e2 = *(const float2*)(xp + 4), e3 = *(const float2*)(xp + 6),
           e4 = *(const float2*)(xp + 8);
    float2 o0 = *(const float2*)(xp + II + 0), o1 = *(const float2*)(xp + II + 2),
           o2 = *(const float2*)(xp + II + 4), o3 = *(const float2*)(xp + II + 6),
           o4 = *(const float2*)(xp + II + 8);

    const bool q0 = (q == 0), q1 = (q == 1);
    const bool w0 = (wp == 0);
    const f32x4 z4 = {0.0f, 0.0f, 0.0f, 0.0f};

    // One timestep (rb compile-time after inlining).
    auto STEP = [&](int rb, float2& l0, float2& l1, float2& l2, float2& l3,
                    float2& l4, int pf) {
        // partner's dword pair (single ds_read_b64; latency overlaps Ax MFMAs)
        const int2 Pd = hx2[rb][1 - wp][n][q];

        // B_x: k=q*8+j -> q0:{x0..x7}, q1:{x8,x9,1.0,0..}, q2/q3: 0
        const unsigned d0 = q0 ? pk2(l0.x, l0.y) : (q1 ? pk2(l4.x, l4.y) : 0u);
        const unsigned d1 = q0 ? pk2(l1.x, l1.y) : (q1 ? 0x00003F80u : 0u);
        const unsigned d2 = q0 ? pk2(l2.x, l2.y) : 0u;
        const unsigned d3 = q0 ? pk2(l3.x, l3.y) : 0u;
        const bf16x8 Bx = __builtin_bit_cast(bf16x8, (i32x4){(int)d0, (int)d1, (int)d2, (int)d3});

        f32x4 acc0 = MFMA(Ax[0], Bx, z4);   // x part first: independent of h
        f32x4 acc1 = MFMA(Ax[1], Bx, z4);
        f32x4 acc2 = MFMA(Ax[2], Bx, z4);
        f32x4 acc3 = MFMA(Ax[3], Bx, z4);

        {   // distance-2 prefetch; stays in flight across the raw barrier
            const float* px = xp + (size_t)pf * II;
            l0 = *(const float2*)(px + 0); l1 = *(const float2*)(px + 2);
            l2 = *(const float2*)(px + 4); l3 = *(const float2*)(px + 6);
            l4 = *(const float2*)(px + 8);
        }

        // B_h: own pair at dwords (2wp, 2wp+1), partner pair at the other two
        const i32x4 bh = w0 ? (i32x4){myD0, myD1, Pd.x, Pd.y}
                            : (i32x4){Pd.x, Pd.y, myD0, myD1};
        const bf16x8 Bh = __builtin_bit_cast(bf16x8, bh);
        acc0 = MFMA(Ah[0], Bh, acc0);
        acc1 = MFMA(Ah[1], Bh, acc1);
        acc2 = MFMA(Ah[2], Bh, acc2);
        acc3 = MFMA(Ah[3], Bh, acc3);

        // epilogue: 4 independent unit chains; gates are the 4 C regs
        f32x4 accs[4] = {acc0, acc1, acc2, acc3};
        #pragma unroll
        for (int i = 0; i < 4; ++i) {
            const float ri = frcp(1.0f + fexp2(-accs[i][0]));
            const float rf = frcp(1.0f + fexp2(-accs[i][1]));
            const float rg = frcp(1.0f + fexp2(-accs[i][2]));
            const float ro = frcp(1.0f + fexp2(-accs[i][3]));
            c[i] = rf * c[i] + ri * (2.0f * rg - 1.0f);
            const float rt = frcp(1.0f + fexp2(c[i] * (-2.0f * LOG2E)));
            hv[i] = ro * (2.0f * rt - 1.0f);
        }
        myD0 = (int)pkh(hv[0], hv[1]);          // next step's own B_h pair
        myD1 = (int)pkh(hv[2], hv[3]);
        hx2[1 - rb][wp][n][q] = make_int2(myD0, myD1);

        // LDS-only sync: drain lgkm (write committed + partner read landed),
        // raw barrier; vmcnt (x prefetch) intentionally NOT drained.
        asm volatile("s_waitcnt lgkmcnt(0)" ::: "memory");
        __builtin_amdgcn_s_barrier();
        asm volatile("" ::: "memory");
    };

    #pragma unroll 1
    for (int t = 0; t < TT; t += 2) {
        const int pfe = (t + 2 < TT) ? t + 2 : TT - 1;
        const int pfo = (t + 3 < TT) ? t + 3 : TT - 1;
        STEP(0, e0, e1, e2, e3, e4, pfe);
        STEP(1, o0, o1, o2, o3, o4, pfo);
    }

    // out[row] = sum_u h[row][u]*W_lin[u] + b_lin
    // lane owns units 16wp+4i+q: reduce q-groups (2 shuffles), then 2 waves
    float p = hv[0] * wl[0] + hv[1] * wl[1] + hv[2] * wl[2] + hv[3] * wl[3];
    p += __shfl_xor(p, 16);
    p += __shfl_xor(p, 32);
    if (q == 0) plds[wp * 16 + n] = p;
    __syncthreads();
    if (tid < 16) out[R + tid] = plds[tid] + plds[16 + tid] + b_lin[0];
}

extern "C" void kernel_launch(void* const* d_in, const int* in_sizes, int n_in,
                              void* d_out, int out_size, void* d_ws, size_t ws_size,
                              hipStream_t stream) {
    const float* x     = (const float*)d_in[0];
    const float* h0    = (const float*)d_in[1];
    const float* c0    = (const float*)d_in[2];
    const float* W_ih  = (const float*)d_in[3];
    const float* W_hh  = (const float*)d_in[4];
    const float* b_ih  = (const float*)d_in[5];
    const float* b_hh  = (const float*)d_in[6];
    const float* W_lin = (const float*)d_in[7];
    const float* b_lin = (const float*)d_in[8];
    float* out = (float*)d_out;

    const int B = in_sizes[1] / HH;   // 4096
    dim3 grid(B / 16), block(128);    // 16 rows/block, 2 waves, 1 chain/CU
    lstm_mfma<<<grid, block, 0, stream>>>(x, h0, c0, W_ih, W_hh, b_ih, b_hh, W_lin, b_lin, out);
}

// Round 6
// 330.577 us; speedup vs baseline: 1.0603x; 1.0603x over previous
//
#include <hip/hip_runtime.h>

#define TT 512
#define II 10
#define HH 32
#define LOG2E 1.44269504088896340736f

typedef __attribute__((ext_vector_type(8))) short bf16x8;   // MFMA A/B frag (4 VGPRs)
typedef __attribute__((ext_vector_type(4))) float f32x4;    // MFMA C/D frag
typedef __attribute__((ext_vector_type(4))) int   i32x4;

#define MFMA(A, B, C) __builtin_amdgcn_mfma_f32_16x16x32_bf16((A), (B), (C), 0, 0, 0)

static __device__ __forceinline__ float frcp(float v) { return __builtin_amdgcn_rcpf(v); }
static __device__ __forceinline__ float fexp2(float v) { return __builtin_amdgcn_exp2f(v); }

static __device__ __forceinline__ short bf16rne(float f) {
    unsigned u = __builtin_bit_cast(unsigned, f);
    u += 0x7fffu + ((u >> 16) & 1u);
    return (short)(u >> 16);
}
// {bf16(a) lo, bf16(b) hi} by truncation: 1 v_perm_b32 (off critical path)
static __device__ __forceinline__ unsigned pk2(float a, float b) {
    return __builtin_amdgcn_perm(__builtin_bit_cast(unsigned, b),
                                 __builtin_bit_cast(unsigned, a), 0x07060302u);
}
// {bf16(a) lo, bf16(b) hi} RNE in ONE instruction (on the h critical path)
static __device__ __forceinline__ int cvtpk(float a, float b) {
    int r;
    asm("v_cvt_pk_bf16_f32 %0, %1, %2" : "=v"(r) : "v"(a), "v"(b));
    return r;
}

// MFMA LSTM, exchange-minimal layout, 4 waves / 16 batch rows per block.
// R1-R3: wall time == single-chain step latency; 4 waves/chain minimizes it.
// R5 content (LDS 68-dword m-stride padding, cs = -2*log2e*c tracking,
// v_cvt_pk_bf16_f32 h-pack) passed the PRE-timing check but diverged in one
// of the ~25 post-timing launches -> rare race suspected in the 3-statement
// sync (asm waitcnt / s_barrier intrinsic / empty asm):
// __builtin_amdgcn_s_barrier is IntrNoMem in LLVM, so memory ordering around
// it rests entirely on the asm clobbers; the padded read cluster (single base
// + imm offsets) is highly hoistable. R6 HARDENING: fuse drain+barrier into
// ONE opaque asm block -- no gap for a hoisted ds_read to land in, writes
// cannot sink below, reads cannot rise above; hardware semantics unchanged
// (drain own LDS ops, then arrive). sched_barrier(0) after it pins any
// register-op motion (rule #18). vmcnt (x prefetch) still NOT drained --
// the validated R2 win (~9%) is preserved.
// Weights pre-scaled by log2e (g-gate 2*log2e): unified rcp(1+exp2(-s))
// activations; bias rides the x-MFMA at k=10 with B=1.0.
extern "C" __global__ __launch_bounds__(256)
__attribute__((amdgpu_waves_per_eu(1)))
void lstm_mfma(const float* __restrict__ x,
               const float* __restrict__ h0,
               const float* __restrict__ c0,
               const float* __restrict__ W_ih,
               const float* __restrict__ W_hh,
               const float* __restrict__ b_ih,
               const float* __restrict__ b_hh,
               const float* __restrict__ W_lin,
               const float* __restrict__ b_lin,
               float* __restrict__ out)
{
    // [buf][m*68 + (4n+q)]: m-regions 68 dwords apart (bank-conflict-free)
    __shared__ int   hxp[2][280];
    __shared__ float plds[64];

    const int tid  = threadIdx.x;
    const int w    = tid >> 6;
    const int lane = tid & 63;
    const int n    = lane & 15;        // batch col (and A-frag row m)
    const int q    = lane >> 4;        // k-chunk / C row-group
    const int R    = blockIdx.x * 16;
    const int li   = 4 * n + q;        // this lane's slot within a region

    // ---- A-frags (weights), one-time. A[m=n][k=q*8+j]. ----
    // gate row in subtile s: G = 16s+n -> unit = 4s+(n>>2), gate = n&3.
    // h-part column = pi(k) = 4j+q. x-part column = k (unpermuted).
    const int   gate = n & 3;
    const float sc   = (gate == 2) ? 2.0f * LOG2E : LOG2E;
    bf16x8 AhA, AhB, AxA, AxB;
    #pragma unroll
    for (int st = 0; st < 2; ++st) {
        const int s     = 2 * w + st;
        const int unitm = 4 * s + (n >> 2);
        const int Wr    = gate * HH + unitm;
        bf16x8 ah, ax;
        #pragma unroll
        for (int j = 0; j < 8; ++j) {
            ah[j] = bf16rne(W_hh[Wr * HH + 4 * j + q] * sc);
            const int k = q * 8 + j;
            float xv = 0.0f;
            if (k < II)       xv = W_ih[Wr * II + k] * sc;
            else if (k == II) xv = (b_ih[Wr] + b_hh[Wr]) * sc;   // bias (B has 1.0 at k=10)
            ax[j] = bf16rne(xv);
        }
        if (st == 0) { AhA = ah; AxA = ax; } else { AhB = ah; AxB = ax; }
    }

    const int uA = 8 * w + q, uB = uA + 4;     // units this lane owns (batch n)
    // cs = -2*log2e * c  (c itself never materialized)
    float csA = (-2.0f * LOG2E) * c0[(R + n) * HH + uA];
    float csB = (-2.0f * LOG2E) * c0[(R + n) * HH + uB];
    const float wlA = W_lin[uA], wlB = W_lin[uB];

    // init h -> buf 0 (packed pair, exactly what consumers expect)
    hxp[0][68 * w + li] = cvtpk(h0[(R + n) * HH + uA], h0[(R + n) * HH + uB]);
    __syncthreads();   // one-time full sync is fine

    // x: lane holds its batch row's 10 floats; two reg sets -> prefetch dist 2
    const float* xp = x + (size_t)(R + n) * (TT * II);
    float2 e0 = *(const float2*)(xp + 0), e1 = *(const float2*)(xp + 2),
           e2 = *(const float2*)(xp + 4), e3 = *(const float2*)(xp + 6),
           e4 = *(const float2*)(xp + 8);
    float2 o0 = *(const float2*)(xp + II + 0), o1 = *(const float2*)(xp + II + 2),
           o2 = *(const float2*)(xp + II + 4), o3 = *(const float2*)(xp + II + 6),
           o4 = *(const float2*)(xp + II + 8);

    const bool q0 = (q == 0), q1 = (q == 1);
    const f32x4 z4 = {0.0f, 0.0f, 0.0f, 0.0f};
    float hA = 0.0f, hB = 0.0f;

    // One timestep (rb compile-time after inlining).
    auto STEP = [&](int rb, float2& l0, float2& l1, float2& l2, float2& l3,
                    float2& l4, int pf) {
        // B_h dwords first: 4 reads at 68-dword stride (pairs -> ds_read2_b32,
        // banks differ by 4/8 -> conflict-free)
        const int b0 = hxp[rb][0 * 68 + li];
        const int b1 = hxp[rb][1 * 68 + li];
        const int b2 = hxp[rb][2 * 68 + li];
        const int b3 = hxp[rb][3 * 68 + li];

        // B_x: k=q*8+j -> q0:{x0..x7}, q1:{x8,x9,1.0,0..}, q2/q3: 0
        const unsigned d0 = q0 ? pk2(l0.x, l0.y) : (q1 ? pk2(l4.x, l4.y) : 0u);
        const unsigned d1 = q0 ? pk2(l1.x, l1.y) : (q1 ? 0x00003F80u : 0u);
        const unsigned d2 = q0 ? pk2(l2.x, l2.y) : 0u;
        const unsigned d3 = q0 ? pk2(l3.x, l3.y) : 0u;
        const bf16x8 Bx = __builtin_bit_cast(bf16x8, (i32x4){(int)d0, (int)d1, (int)d2, (int)d3});

        f32x4 accA = MFMA(AxA, Bx, z4);     // x part first: independent of h
        f32x4 accB = MFMA(AxB, Bx, z4);

        {   // distance-2 prefetch; stays in flight across the raw barrier
            const float* px = xp + (size_t)pf * II;
            l0 = *(const float2*)(px + 0); l1 = *(const float2*)(px + 2);
            l2 = *(const float2*)(px + 4); l3 = *(const float2*)(px + 6);
            l4 = *(const float2*)(px + 8);
        }

        const bf16x8 Bh = __builtin_bit_cast(bf16x8, (i32x4){b0, b1, b2, b3});
        accA = MFMA(AhA, Bh, accA);
        accB = MFMA(AhB, Bh, accB);

        // epilogue: gates are the 4 C regs (pre-scaled) -> unified activation.
        // critical chain: exp2(-f) -> rcp -> fma(cs) -> exp2(cs) -> rcp -> h
        {
            const float ri = frcp(1.0f + fexp2(-accA[0]));
            const float rf = frcp(1.0f + fexp2(-accA[1]));
            const float rg = frcp(1.0f + fexp2(-accA[2]));
            const float ro = frcp(1.0f + fexp2(-accA[3]));
            csA = rf * csA + (-2.0f * LOG2E) * (ri * (2.0f * rg - 1.0f));
            const float rt = frcp(1.0f + fexp2(csA));
            hA = ro * (2.0f * rt - 1.0f);
        }
        {
            const float ri = frcp(1.0f + fexp2(-accB[0]));
            const float rf = frcp(1.0f + fexp2(-accB[1]));
            const float rg = frcp(1.0f + fexp2(-accB[2]));
            const float ro = frcp(1.0f + fexp2(-accB[3]));
            csB = rf * csB + (-2.0f * LOG2E) * (ri * (2.0f * rg - 1.0f));
            const float rt = frcp(1.0f + fexp2(csB));
            hB = ro * (2.0f * rt - 1.0f);
        }
        hxp[1 - rb][68 * w + li] = cvtpk(hA, hB);   // next step's B_h dword

        // LDS sync, ONE opaque asm block: drain own LDS ops then arrive.
        // Fused so no hoisted memory op can land between waitcnt and barrier;
        // memory clobber orders the write above and the reads below.
        // vmcnt (x prefetch) intentionally NOT drained.
        asm volatile("s_waitcnt lgkmcnt(0)\n\ts_barrier" ::: "memory");
        __builtin_amdgcn_sched_barrier(0);
    };

    #pragma unroll 1
    for (int t = 0; t < TT; t += 2) {
        const int pfe = (t + 2 < TT) ? t + 2 : TT - 1;
        const int pfo = (t + 3 < TT) ? t + 3 : TT - 1;
        STEP(0, e0, e1, e2, e3, e4, pfe);
        STEP(1, o0, o1, o2, o3, o4, pfo);
    }

    // out[R+n] = sum_u h[n][u]*W_lin[u] + b_lin: reduce over q-groups then waves
    float p = hA * wlA + hB * wlB;
    p += __shfl_xor(p, 16);
    p += __shfl_xor(p, 32);
    if (q == 0) plds[w * 16 + n] = p;
    __syncthreads();
    if (tid < 16) {
        out[R + tid] = plds[tid] + plds[16 + tid] + plds[32 + tid] + plds[48 + tid] + b_lin[0];
    }
}

extern "C" void kernel_launch(void* const* d_in, const int* in_sizes, int n_in,
                              void* d_out, int out_size, void* d_ws, size_t ws_size,
                              hipStream_t stream) {
    const float* x     = (const float*)d_in[0];
    const float* h0    = (const float*)d_in[1];
    const float* c0    = (const float*)d_in[2];
    const float* W_ih  = (const float*)d_in[3];
    const float* W_hh  = (const float*)d_in[4];
    const float* b_ih  = (const float*)d_in[5];
    const float* b_hh  = (const float*)d_in[6];
    const float* W_lin = (const float*)d_in[7];
    const float* b_lin = (const float*)d_in[8];
    float* out = (float*)d_out;

    const int B = in_sizes[1] / HH;   // 4096
    dim3 grid(B / 16), block(256);    // 16 rows/block, 4 waves, 1 chain/CU
    lstm_mfma<<<grid, block, 0, stream>>>(x, h0, c0, W_ih, W_hh, b_ih, b_hh, W_lin, b_lin, out);
}

// Round 7
// 328.113 us; speedup vs baseline: 1.0683x; 1.0075x over previous
//
#include <hip/hip_runtime.h>

#define TT 512
#define II 10
#define HH 32
#define LOG2E 1.44269504088896340736f

typedef __attribute__((ext_vector_type(8))) short bf16x8;   // MFMA A/B frag (4 VGPRs)
typedef __attribute__((ext_vector_type(4))) float f32x4;    // MFMA C/D frag
typedef __attribute__((ext_vector_type(4))) int   i32x4;

#define MFMA(A, B, C) __builtin_amdgcn_mfma_f32_16x16x32_bf16((A), (B), (C), 0, 0, 0)

static __device__ __forceinline__ float frcp(float v) { return __builtin_amdgcn_rcpf(v); }
static __device__ __forceinline__ float fexp2(float v) { return __builtin_amdgcn_exp2f(v); }

static __device__ __forceinline__ short bf16rne(float f) {
    unsigned u = __builtin_bit_cast(unsigned, f);
    u += 0x7fffu + ((u >> 16) & 1u);
    return (short)(u >> 16);
}
// {bf16(a) lo, bf16(b) hi} by truncation: 1 v_perm_b32 (off critical path)
static __device__ __forceinline__ unsigned pk2(float a, float b) {
    return __builtin_amdgcn_perm(__builtin_bit_cast(unsigned, b),
                                 __builtin_bit_cast(unsigned, a), 0x07060302u);
}
// {bf16(a) lo, bf16(b) hi} RNE in ONE instruction (on the h critical path)
static __device__ __forceinline__ int cvtpk(float a, float b) {
    int r;
    asm("v_cvt_pk_bf16_f32 %0, %1, %2" : "=v"(r) : "v"(a), "v"(b));
    return r;
}

// MFMA LSTM, exchange-minimal layout, 4 waves / 16 batch rows per block.
// R1-R3: wall time == single-chain step latency (256 chains / 256 CUs);
// 4 waves/chain minimizes it. R6 evidence: SQ_LDS_BANK_CONFLICT is
// bit-identical (5.24M = 40/block-step = 2 per wave64 LDS access) for padded
// and unpadded layouts -> it is the INHERENT 64-lane/32-bank 2-way aliasing
// (free per throughput), not a fixable cost. Sync is the R6-hardened fused
// asm {s_waitcnt lgkmcnt(0); s_barrier} + sched_barrier(0): one opaque block,
// no hoist gap (R5's 3-statement sync raced rarely). vmcnt (x prefetch) is
// intentionally NOT drained across the barrier (R2: draining costs ~9%).
//
// R7: RATIONAL EPILOGUE -- per-SIMD issue is dominated by transcendentals
// (20/wave-step @ ~8cy). Rewrite gates as rationals in X=2^-acc:
//   sigmoid(s)=1/(1+X), tanh(g)=(1-G)/(1+G), and combine the c-update over a
//   common denominator:  c' = [c(1+A)(1+G) + (1-G)(1+F)] / [(1+F)(1+A)(1+G)]
//   h  = (1-C) / [(1+O)(1+C)],  C = 2^(c'(-2log2e))
// => 5 exp2 + 2 rcp = 7 trans/unit (was 10), +3 VALU. ~-36 issue-cy/step.
// Weights pre-scaled by log2e (g-gate 2*log2e); bias rides the x-MFMA at
// k=10 with B=1.0. c is carried PLAIN (not pre-scaled) this round.
extern "C" __global__ __launch_bounds__(256)
__attribute__((amdgpu_waves_per_eu(1)))
void lstm_mfma(const float* __restrict__ x,
               const float* __restrict__ h0,
               const float* __restrict__ c0,
               const float* __restrict__ W_ih,
               const float* __restrict__ W_hh,
               const float* __restrict__ b_ih,
               const float* __restrict__ b_hh,
               const float* __restrict__ W_lin,
               const float* __restrict__ b_lin,
               float* __restrict__ out)
{
    // [buf][m*68 + (4n+q)] (padding kept from R6 -- neutral, avoids churn)
    __shared__ int   hxp[2][280];
    __shared__ float plds[64];

    const int tid  = threadIdx.x;
    const int w    = tid >> 6;
    const int lane = tid & 63;
    const int n    = lane & 15;        // batch col (and A-frag row m)
    const int q    = lane >> 4;        // k-chunk / C row-group
    const int R    = blockIdx.x * 16;
    const int li   = 4 * n + q;        // this lane's slot within a region

    // ---- A-frags (weights), one-time. A[m=n][k=q*8+j]. ----
    // gate row in subtile s: G = 16s+n -> unit = 4s+(n>>2), gate = n&3.
    // h-part column = pi(k) = 4j+q. x-part column = k (unpermuted).
    const int   gate = n & 3;
    const float sc   = (gate == 2) ? 2.0f * LOG2E : LOG2E;
    bf16x8 AhA, AhB, AxA, AxB;
    #pragma unroll
    for (int st = 0; st < 2; ++st) {
        const int s     = 2 * w + st;
        const int unitm = 4 * s + (n >> 2);
        const int Wr    = gate * HH + unitm;
        bf16x8 ah, ax;
        #pragma unroll
        for (int j = 0; j < 8; ++j) {
            ah[j] = bf16rne(W_hh[Wr * HH + 4 * j + q] * sc);
            const int k = q * 8 + j;
            float xv = 0.0f;
            if (k < II)       xv = W_ih[Wr * II + k] * sc;
            else if (k == II) xv = (b_ih[Wr] + b_hh[Wr]) * sc;   // bias (B has 1.0 at k=10)
            ax[j] = bf16rne(xv);
        }
        if (st == 0) { AhA = ah; AxA = ax; } else { AhB = ah; AxB = ax; }
    }

    const int uA = 8 * w + q, uB = uA + 4;     // units this lane owns (batch n)
    float cA = c0[(R + n) * HH + uA];          // plain c carry
    float cB = c0[(R + n) * HH + uB];
    const float wlA = W_lin[uA], wlB = W_lin[uB];

    // init h -> buf 0 (packed pair, exactly what consumers expect)
    hxp[0][68 * w + li] = cvtpk(h0[(R + n) * HH + uA], h0[(R + n) * HH + uB]);
    __syncthreads();   // one-time full sync is fine

    // x: lane holds its batch row's 10 floats; two reg sets -> prefetch dist 2
    const float* xp = x + (size_t)(R + n) * (TT * II);
    float2 e0 = *(const float2*)(xp + 0), e1 = *(const float2*)(xp + 2),
           e2 = *(const float2*)(xp + 4), e3 = *(const float2*)(xp + 6),
           e4 = *(const float2*)(xp + 8);
    float2 o0 = *(const float2*)(xp + II + 0), o1 = *(const float2*)(xp + II + 2),
           o2 = *(const float2*)(xp + II + 4), o3 = *(const float2*)(xp + II + 6),
           o4 = *(const float2*)(xp + II + 8);

    const bool q0 = (q == 0), q1 = (q == 1);
    const f32x4 z4 = {0.0f, 0.0f, 0.0f, 0.0f};
    float hA = 0.0f, hB = 0.0f;

    // Rational LSTM cell: acc = (ai, af, ag, ao) pre-scaled by log2e
    // (g-gate by 2log2e). 5 exp2 + 2 rcp; overflow-safe for |gate|<~25.
    auto CELL = [&](const f32x4& acc, float& c, float& h) {
        const float A = fexp2(-acc[0]);
        const float F = fexp2(-acc[1]);
        const float G = fexp2(-acc[2]);
        const float O = fexp2(-acc[3]);
        const float onF = 1.0f + F;
        const float u   = (1.0f + A) * (1.0f + G);
        const float wn  = (1.0f - G) * onF;
        const float num = c * u + wn;                  // fma
        const float rD  = frcp(onF * u);
        c = num * rD;                                  // c'
        const float C   = fexp2(c * (-2.0f * LOG2E));
        const float rv  = frcp((1.0f + O) * (1.0f + C));
        h = (1.0f - C) * rv;                           // o * tanh(c')
    };

    // One timestep (rb compile-time after inlining).
    auto STEP = [&](int rb, float2& l0, float2& l1, float2& l2, float2& l3,
                    float2& l4, int pf) {
        // B_h dwords first: read latency overlapped by Bx pack + Ax MFMAs
        const int b0 = hxp[rb][0 * 68 + li];
        const int b1 = hxp[rb][1 * 68 + li];
        const int b2 = hxp[rb][2 * 68 + li];
        const int b3 = hxp[rb][3 * 68 + li];

        // B_x: k=q*8+j -> q0:{x0..x7}, q1:{x8,x9,1.0,0..}, q2/q3: 0
        const unsigned d0 = q0 ? pk2(l0.x, l0.y) : (q1 ? pk2(l4.x, l4.y) : 0u);
        const unsigned d1 = q0 ? pk2(l1.x, l1.y) : (q1 ? 0x00003F80u : 0u);
        const unsigned d2 = q0 ? pk2(l2.x, l2.y) : 0u;
        const unsigned d3 = q0 ? pk2(l3.x, l3.y) : 0u;
        const bf16x8 Bx = __builtin_bit_cast(bf16x8, (i32x4){(int)d0, (int)d1, (int)d2, (int)d3});

        f32x4 accA = MFMA(AxA, Bx, z4);     // x part first: independent of h
        f32x4 accB = MFMA(AxB, Bx, z4);

        {   // distance-2 prefetch; stays in flight across the raw barrier
            const float* px = xp + (size_t)pf * II;
            l0 = *(const float2*)(px + 0); l1 = *(const float2*)(px + 2);
            l2 = *(const float2*)(px + 4); l3 = *(const float2*)(px + 6);
            l4 = *(const float2*)(px + 8);
        }

        const bf16x8 Bh = __builtin_bit_cast(bf16x8, (i32x4){b0, b1, b2, b3});
        accA = MFMA(AhA, Bh, accA);
        accB = MFMA(AhB, Bh, accB);

        CELL(accA, cA, hA);                 // two independent chains (ILP)
        CELL(accB, cB, hB);
        hxp[1 - rb][68 * w + li] = cvtpk(hA, hB);   // next step's B_h dword

        // LDS sync, ONE opaque asm block (R6-hardened): drain own LDS ops
        // then arrive; no gap for hoisted memory ops; vmcnt NOT drained.
        asm volatile("s_waitcnt lgkmcnt(0)\n\ts_barrier" ::: "memory");
        __builtin_amdgcn_sched_barrier(0);
    };

    #pragma unroll 1
    for (int t = 0; t < TT; t += 2) {
        const int pfe = (t + 2 < TT) ? t + 2 : TT - 1;
        const int pfo = (t + 3 < TT) ? t + 3 : TT - 1;
        STEP(0, e0, e1, e2, e3, e4, pfe);
        STEP(1, o0, o1, o2, o3, o4, pfo);
    }

    // out[R+n] = sum_u h[n][u]*W_lin[u] + b_lin: reduce over q-groups then waves
    float p = hA * wlA + hB * wlB;
    p += __shfl_xor(p, 16);
    p += __shfl_xor(p, 32);
    if (q == 0) plds[w * 16 + n] = p;
    __syncthreads();
    if (tid < 16) {
        out[R + tid] = plds[tid] + plds[16 + tid] + plds[32 + tid] + plds[48 + tid] + b_lin[0];
    }
}

extern "C" void kernel_launch(void* const* d_in, const int* in_sizes, int n_in,
                              void* d_out, int out_size, void* d_ws, size_t ws_size,
                              hipStream_t stream) {
    const float* x     = (const float*)d_in[0];
    const float* h0    = (const float*)d_in[1];
    const float* c0    = (const float*)d_in[2];
    const float* W_ih  = (const float*)d_in[3];
    const float* W_hh  = (const float*)d_in[4];
    const float* b_ih  = (const float*)d_in[5];
    const float* b_hh  = (const float*)d_in[6];
    const float* W_lin = (const float*)d_in[7];
    const float* b_lin = (const float*)d_in[8];
    float* out = (float*)d_out;

    const int B = in_sizes[1] / HH;   // 4096
    dim3 grid(B / 16), block(256);    // 16 rows/block, 4 waves, 1 chain/CU
    lstm_mfma<<<grid, block, 0, stream>>>(x, h0, c0, W_ih, W_hh, b_ih, b_hh, W_lin, b_lin, out);
}